// Round 9
// baseline (288.801 us; speedup 1.0000x reference)
//
#include <hip/hip_runtime.h>

// 3D spatial correlation sampler — R9 ABLATION ROUND.
// V0 = real R8 kernel (validates, writes d_out).
// V3 = V0 minus output stores (acc sunk via asm).
// V1 = V3 minus FMAs (LDS reads + loads kept live via asm sinks).
// V2 = V3 minus stage/vmcnt/barrier/LDS-read complex (in1 loads + FMAs only;
//      LDS still allocated+touched so occupancy bound matches).
// Attribution: stores=V0-V3, FMA=V3-V1, stage-complex=V3-V2 (per-dispatch
// dur_us from rocprof; bench dur_us is the 4-kernel sum this round).

#define BB 2
#define CC 32
#define DD 32
#define HH 32
#define WW 32
#define PP 7
#define RR 3
#define PLANE 1024
#define CH_STRIDE 32768
#define CH_BYTES (CH_STRIDE * 4)
#define NWG (49 * 16 * 2)        // 1568 = 8 * 196
#define NWG_PER_XCD (NWG / 8)    // 196

#define ROW_BYTES 176            // 16B left pad | 128B data | 32B right pad
#define REGION_BYTES 6144
#define BUF_BYTES (2 * REGION_BYTES)   // 12288
#define LDS_BYTES (2 * BUF_BYTES)      // 24576

#define SINK1(x) asm volatile("" :: "v"(x))
#define SINK4(v) asm volatile("" :: "v"((v).x), "v"((v).y), "v"((v).z), "v"((v).w))

#define STAGE(BFN) do {                                                        \
    __builtin_amdgcn_global_load_lds(                                          \
        (const __attribute__((address_space(1))) void*)sg0,                    \
        (__attribute__((address_space(3))) void*)(lds_dst + (BFN)*BUF_BYTES),  \
        16, 0, 0);                                                             \
    __builtin_amdgcn_global_load_lds(                                          \
        (const __attribute__((address_space(1))) void*)sg1,                    \
        (__attribute__((address_space(3))) void*)(lds_dst + (BFN)*BUF_BYTES + 1024), \
        16, 0, 0);                                                             \
    __builtin_amdgcn_global_load_lds(                                          \
        (const __attribute__((address_space(1))) void*)sg2,                    \
        (__attribute__((address_space(3))) void*)(lds_dst + (BFN)*BUF_BYTES + 2048), \
        16, 0, 0);                                                             \
    sg0 += CH_BYTES; sg1 += CH_BYTES; sg2 += CH_BYTES;                         \
} while (0)

#define FMALOOP(A_, WIN_) do {                                                 \
    _Pragma("unroll")                                                          \
    for (int i = 0; i < 8; ++i)                                                \
        _Pragma("unroll")                                                      \
        for (int p = 0; p < 7; ++p)                                            \
            acc[i][p] = fmaf(A_[i], WIN_[i + p + 1], acc[i][p]);               \
} while (0)

// One pipeline phase: stage(c+1), prefetch in1(c+1) into S, consume R (=c).
#define PHASEX(R0, R1, S0, S1, BF) do {                                        \
    if constexpr (DO_STAGE) STAGE((BF) ^ 1);                                   \
    S0 = *(const float4*)(p1);                                                 \
    S1 = *(const float4*)(p1 + 4);                                             \
    p1 += CH_STRIDE;                                                           \
    if constexpr (DO_STAGE) {                                                  \
        asm volatile("s_waitcnt vmcnt(5)" ::: "memory");                       \
        __builtin_amdgcn_s_barrier();                                          \
        __builtin_amdgcn_sched_barrier(0);                                     \
    }                                                                          \
    if constexpr (DO_STAGE) {                                                  \
        const char* bp = smem + (BF) * BUF_BYTES + rdoff;                      \
        float4 q0 = *(const float4*)(bp);                                      \
        float4 q1 = *(const float4*)(bp + 16);                                 \
        float4 q2 = *(const float4*)(bp + 32);                                 \
        float4 q3 = *(const float4*)(bp + 48);                                 \
        if (!lv)  q0 = make_float4(0.f, 0.f, 0.f, 0.f);                       \
        if (!rvb) q3 = make_float4(0.f, 0.f, 0.f, 0.f);                       \
        if constexpr (DO_FMA) {                                                \
            const float a_[8]   = {R0.x, R0.y, R0.z, R0.w,                     \
                                   R1.x, R1.y, R1.z, R1.w};                    \
            const float win[16] = {q0.x, q0.y, q0.z, q0.w,                     \
                                   q1.x, q1.y, q1.z, q1.w,                     \
                                   q2.x, q2.y, q2.z, q2.w,                     \
                                   q3.x, q3.y, q3.z, q3.w};                    \
            FMALOOP(a_, win);                                                  \
        } else {                                                               \
            SINK4(q0); SINK4(q1); SINK4(q2); SINK4(q3);                        \
            SINK4(R0); SINK4(R1);                                              \
        }                                                                      \
    } else {                                                                   \
        /* V2: window faked from R regs (prev-phase data, same dep distance) */\
        const float a_[8]   = {R0.x, R0.y, R0.z, R0.w,                         \
                               R1.x, R1.y, R1.z, R1.w};                        \
        const float win[16] = {R0.x, R0.y, R0.z, R0.w,                         \
                               R1.x, R1.y, R1.z, R1.w,                         \
                               R0.x, R0.y, R0.z, R0.w,                         \
                               R1.x, R1.y, R1.z, R1.w};                        \
        FMALOOP(a_, win);                                                      \
    }                                                                          \
    if constexpr (DO_STAGE) {                                                  \
        __builtin_amdgcn_sched_barrier(0);                                     \
        __builtin_amdgcn_s_barrier();                                          \
    }                                                                          \
} while (0)

#define PHASELAST(R0, R1, BF) do {                                             \
    if constexpr (DO_STAGE) {                                                  \
        asm volatile("s_waitcnt vmcnt(0)" ::: "memory");                       \
        __builtin_amdgcn_s_barrier();                                          \
        __builtin_amdgcn_sched_barrier(0);                                     \
        const char* bp = smem + (BF) * BUF_BYTES + rdoff;                      \
        float4 q0 = *(const float4*)(bp);                                      \
        float4 q1 = *(const float4*)(bp + 16);                                 \
        float4 q2 = *(const float4*)(bp + 32);                                 \
        float4 q3 = *(const float4*)(bp + 48);                                 \
        if (!lv)  q0 = make_float4(0.f, 0.f, 0.f, 0.f);                       \
        if (!rvb) q3 = make_float4(0.f, 0.f, 0.f, 0.f);                       \
        if constexpr (DO_FMA) {                                                \
            const float a_[8]   = {R0.x, R0.y, R0.z, R0.w,                     \
                                   R1.x, R1.y, R1.z, R1.w};                    \
            const float win[16] = {q0.x, q0.y, q0.z, q0.w,                     \
                                   q1.x, q1.y, q1.z, q1.w,                     \
                                   q2.x, q2.y, q2.z, q2.w,                     \
                                   q3.x, q3.y, q3.z, q3.w};                    \
            FMALOOP(a_, win);                                                  \
        } else {                                                               \
            SINK4(q0); SINK4(q1); SINK4(q2); SINK4(q3);                        \
            SINK4(R0); SINK4(R1);                                              \
        }                                                                      \
    } else {                                                                   \
        const float a_[8]   = {R0.x, R0.y, R0.z, R0.w,                         \
                               R1.x, R1.y, R1.z, R1.w};                        \
        const float win[16] = {R0.x, R0.y, R0.z, R0.w,                         \
                               R1.x, R1.y, R1.z, R1.w,                         \
                               R0.x, R0.y, R0.z, R0.w,                         \
                               R1.x, R1.y, R1.z, R1.w};                        \
        FMALOOP(a_, win);                                                      \
    }                                                                          \
} while (0)

template <int V>
__global__ __launch_bounds__(256) void corr3d_abl(
    const float* __restrict__ in1,
    const float* __restrict__ in2,
    float* __restrict__ out) {
    constexpr bool DO_STAGE = (V != 2);
    constexpr bool DO_FMA   = (V != 1);
    constexpr bool DO_STORE = (V == 0);

    __shared__ __align__(16) char smem[LDS_BYTES];

    const int tid  = threadIdx.x;
    const int lane = tid & 63;
    const int wv   = tid >> 6;

    const int j = blockIdx.x;
    int bi = (j & 7) * NWG_PER_XCD + (j >> 3);
    const int off = bi % 49; bi /= 49;
    const int d2  = bi % 16; bi /= 16;
    const int b   = bi;
    const int pd  = off / 7;
    const int ph  = off % 7;

    const int wb = tid & 3;
    const int w0 = wb << 3;
    const int h  = (tid >> 2) & 31;
    const int dd = tid >> 7;
    const int d0 = d2 * 2;
    const int d  = d0 + dd;

    const int dz = d + pd - RR;
    const int hy = h + ph - RR;
    const bool pv = (unsigned)dz < DD;
    const bool rv = (unsigned)hy < HH;
    const int hyc = hy < 0 ? 0 : (hy > HH - 1 ? HH - 1 : hy);
    const bool lv  = (wb != 0);
    const bool rvb = (wb != 3);

    if constexpr (!DO_STAGE) {
        // keep the LDS allocation alive so occupancy bound matches V0
        int t = *(volatile int*)(smem + tid * 96);
        SINK1(t);
    }

    const int r = wv & 1;
    int dzr = d0 + r + pd - RR;
    dzr = dzr < 0 ? 0 : (dzr > DD - 1 ? DD - 1 : dzr);
    const char* src_plane =
        (const char*)(in2 + ((size_t)(b * CC * DD + dzr)) * PLANE);
    const int qbase = (wv >> 1) * 192 + lane;
    const char* sg0; const char* sg1; const char* sg2;
    {
#define SRCOFF(q, dst) do {                                                    \
        int row_ = ((q) * 5958) >> 16;                                         \
        int c16_ = (q) - row_ * 11;                                            \
        if (row_ > 31) row_ = 31;                                              \
        int colb_ = (c16_ == 0) ? 0 : (c16_ >= 9 ? 112 : (c16_ - 1) * 16);     \
        dst = src_plane + row_ * 128 + colb_;                                  \
} while (0)
        SRCOFF(qbase,        sg0);
        SRCOFF(qbase + 64,   sg1);
        SRCOFF(qbase + 128,  sg2);
#undef SRCOFF
    }
    char* lds_dst = smem + r * REGION_BYTES + (wv >> 1) * 3072;

    const float* p1 = in1 + ((size_t)(b * CC * DD + d)) * PLANE + h * WW + w0;
    const int rdoff = dd * REGION_BYTES + hyc * ROW_BYTES + wb * 32;

    float acc[8][7];
#pragma unroll
    for (int i = 0; i < 8; ++i)
#pragma unroll
        for (int p = 0; p < 7; ++p) acc[i][p] = 0.f;

    if constexpr (DO_STAGE) STAGE(0);
    float4 A0 = *(const float4*)(p1);
    float4 A1 = *(const float4*)(p1 + 4);
    p1 += CH_STRIDE;
    float4 B0, B1;

#pragma unroll 1
    for (int it = 0; it < 15; ++it) {
        PHASEX(A0, A1, B0, B1, 0);
        PHASEX(B0, B1, A0, A1, 1);
    }
    PHASEX(A0, A1, B0, B1, 0);
    PHASELAST(B0, B1, 1);

    if constexpr (DO_STORE) {
        if (!(pv && rv)) {
#pragma unroll
            for (int i = 0; i < 8; ++i)
#pragma unroll
                for (int p = 0; p < 7; ++p) acc[i][p] = 0.f;
        }
        float* po = out + (((size_t)(b * 49 + pd * 7 + ph)) * PP) * CH_STRIDE
                        + (size_t)d * PLANE + h * WW + w0;
#pragma unroll
        for (int p = 0; p < 7; ++p) {
            *(float4*)(po)     = make_float4(acc[0][p], acc[1][p], acc[2][p], acc[3][p]);
            *(float4*)(po + 4) = make_float4(acc[4][p], acc[5][p], acc[6][p], acc[7][p]);
            po += CH_STRIDE;
        }
    } else {
#pragma unroll
        for (int i = 0; i < 8; ++i)
#pragma unroll
            for (int p = 0; p < 7; ++p) SINK1(acc[i][p]);
    }
}

extern "C" void kernel_launch(void* const* d_in, const int* in_sizes, int n_in,
                              void* d_out, int out_size, void* d_ws, size_t ws_size,
                              hipStream_t stream) {
    const float* in1 = (const float*)d_in[0];
    const float* in2 = (const float*)d_in[1];
    float* out = (float*)d_out;
    dim3 grid(NWG);
    dim3 block(256);
    // V0: real kernel (validates). V3/V1/V2: timing probes, no memory writes.
    hipLaunchKernelGGL(corr3d_abl<0>, grid, block, 0, stream, in1, in2, out);
    hipLaunchKernelGGL(corr3d_abl<3>, grid, block, 0, stream, in1, in2, out);
    hipLaunchKernelGGL(corr3d_abl<1>, grid, block, 0, stream, in1, in2, out);
    hipLaunchKernelGGL(corr3d_abl<2>, grid, block, 0, stream, in1, in2, out);
}